// Round 1
// baseline (1792.930 us; speedup 1.0000x reference)
//
#include <hip/hip_runtime.h>
#include <math.h>

#define B_ 64
#define M_ 1024
#define K_ 16
#define H_ 64
#define N_ (B_*M_)   // 65536

// ---------------- encoder: h = relu(relu(x@w1+b1)@w2+b2) ----------------
__global__ __launch_bounds__(256) void enc_kernel(
    const float* __restrict__ x,     // [N,4]
    const float* __restrict__ w1,    // [4,32]
    const float* __restrict__ b1,    // [32]
    const float* __restrict__ w2,    // [32,64]
    const float* __restrict__ b2,    // [64]
    float* __restrict__ h)           // [N,64]
{
    __shared__ float sw1[4*32];
    __shared__ float sb1[32];
    __shared__ float sw2[32*64];
    __shared__ float sb2[64];
    int t = threadIdx.x;
    for (int i = t; i < 128; i += 256) sw1[i] = w1[i];
    if (t < 32) sb1[t] = b1[t];
    for (int i = t; i < 2048; i += 256) sw2[i] = w2[i];
    if (t < 64) sb2[t] = b2[t];
    __syncthreads();
    int n = blockIdx.x * 256 + t;
    float4 xv = *(const float4*)(x + (size_t)n*4);
    float hid[32];
    #pragma unroll
    for (int o = 0; o < 32; ++o) {
        float a = sb1[o] + xv.x*sw1[0*32+o] + xv.y*sw1[1*32+o]
                        + xv.z*sw1[2*32+o] + xv.w*sw1[3*32+o];
        hid[o] = fmaxf(a, 0.f);
    }
    float* hout = h + (size_t)n*64;
    #pragma unroll 4
    for (int oc = 0; oc < 16; ++oc) {
        float4 acc = make_float4(sb2[oc*4+0], sb2[oc*4+1], sb2[oc*4+2], sb2[oc*4+3]);
        #pragma unroll
        for (int f = 0; f < 32; ++f) {
            float4 w = *(const float4*)(sw2 + f*64 + oc*4);
            float hv = hid[f];
            acc.x += hv*w.x; acc.y += hv*w.y; acc.z += hv*w.z; acc.w += hv*w.w;
        }
        acc.x = fmaxf(acc.x,0.f); acc.y = fmaxf(acc.y,0.f);
        acc.z = fmaxf(acc.z,0.f); acc.w = fmaxf(acc.w,0.f);
        *(float4*)(hout + oc*4) = acc;
    }
}

// ---------------- kNN: 16 nearest (excl self) per node ----------------
// one wave per block; thread = one query node i; stream j-tiles through LDS
__global__ __launch_bounds__(64) void knn_kernel(
    const float* __restrict__ h,   // [N,64]
    int* __restrict__ knn)         // [N,16] (local node ids within graph)
{
    __shared__ float hj[64*64];
    __shared__ float sqj[64];
    int lane = threadIdx.x;
    int b  = blockIdx.x >> 4;
    int it = blockIdx.x & 15;
    int i  = it*64 + lane;               // local node id in graph
    const float* hb = h + (size_t)b*M_*H_;
    float4 hi[16];
    #pragma unroll
    for (int c = 0; c < 16; ++c) hi[c] = *(const float4*)(hb + (size_t)i*64 + c*4);
    float sqi = 0.f;
    #pragma unroll
    for (int c = 0; c < 16; ++c)
        sqi += hi[c].x*hi[c].x + hi[c].y*hi[c].y + hi[c].z*hi[c].z + hi[c].w*hi[c].w;

    float bd[16]; int bi[16];
    #pragma unroll
    for (int k = 0; k < 16; ++k) { bd[k] = INFINITY; bi[k] = 0; }
    float worst = INFINITY; int wslot = 0;

    for (int jt = 0; jt < 16; ++jt) {
        __syncthreads();
        {   // stage row j = jt*64 + lane, accumulate its sq
            float s = 0.f;
            const float* src = hb + (size_t)(jt*64 + lane)*64;
            #pragma unroll
            for (int c = 0; c < 16; ++c) {
                float4 v = *(const float4*)(src + c*4);
                *(float4*)(hj + lane*64 + c*4) = v;
                s += v.x*v.x + v.y*v.y + v.z*v.z + v.w*v.w;
            }
            sqj[lane] = s;
        }
        __syncthreads();
        #pragma unroll 4
        for (int j = 0; j < 64; ++j) {
            const float* r = hj + j*64;
            float4 a0 = make_float4(0.f,0.f,0.f,0.f);
            #pragma unroll
            for (int c = 0; c < 16; ++c) {
                float4 v = *(const float4*)(r + c*4);
                a0.x += hi[c].x*v.x; a0.y += hi[c].y*v.y;
                a0.z += hi[c].z*v.z; a0.w += hi[c].w*v.w;
            }
            float dot = (a0.x + a0.y) + (a0.z + a0.w);
            int jg = jt*64 + j;
            float d = sqi + sqj[j] - 2.f*dot;
            if ((jg != i) && (d < worst)) {
                #pragma unroll
                for (int k = 0; k < 16; ++k) if (k == wslot) { bd[k] = d; bi[k] = jg; }
                worst = bd[0]; wslot = 0;
                #pragma unroll
                for (int k = 1; k < 16; ++k) if (bd[k] > worst) { worst = bd[k]; wslot = k; }
            }
        }
    }
    size_t gi = (size_t)b*M_ + i;
    #pragma unroll
    for (int k = 0; k < 16; ++k) knn[gi*16 + k] = bi[k];
}

// ---------------- A = h @ W1b  (W1b = rows 64..127 of w1) ----------------
__global__ __launch_bounds__(256) void gemmA_kernel(
    const float* __restrict__ h,
    const float* __restrict__ w1,   // [128,64]
    float* __restrict__ A)
{
    __shared__ float sw[64*64];
    int t = threadIdx.x;
    for (int idx = t; idx < 4096; idx += 256) sw[idx] = w1[4096 + idx];
    __syncthreads();
    int n = blockIdx.x * 256 + t;
    float4 hv[16];
    const float* src = h + (size_t)n*64;
    #pragma unroll
    for (int c = 0; c < 16; ++c) hv[c] = *(const float4*)(src + c*4);
    float* dst = A + (size_t)n*64;
    #pragma unroll 2
    for (int oc = 0; oc < 16; ++oc) {
        float4 acc = make_float4(0.f,0.f,0.f,0.f);
        #pragma unroll
        for (int f = 0; f < 64; ++f) {
            float xv = ((const float*)hv)[f];
            float4 w = *(const float4*)(sw + f*64 + oc*4);
            acc.x += xv*w.x; acc.y += xv*w.y; acc.z += xv*w.z; acc.w += xv*w.w;
        }
        *(float4*)(dst + oc*4) = acc;
    }
}

// ---------------- EdgeConv: out_i = max_e ReLU(C_i + A_j)@W2 + b2 ----------------
#define RS 20   // padded row stride for hidT
__global__ __launch_bounds__(256) void edge_kernel(
    const float* __restrict__ h,     // [N,64] in (in-place out OK: only own row read)
    const float* __restrict__ A,     // [N,64]
    const int* __restrict__ knn,     // [N,16] local idx
    const float* __restrict__ w1,    // [128,64]
    const float* __restrict__ b1,    // [64]
    const float* __restrict__ w2,    // [64,64]
    const float* __restrict__ b2,    // [64]
    float* __restrict__ hout)
{
    __shared__ float swd[64*64];   // W1a - W1b
    __shared__ float sw2[64*64];
    __shared__ float sb1[64], sb2[64];
    __shared__ float hS[4][64];
    __shared__ float hidT[4][64*RS];
    int t = threadIdx.x;
    for (int idx = t; idx < 4096; idx += 256) {
        swd[idx] = w1[idx] - w1[4096 + idx];
        sw2[idx] = w2[idx];
    }
    if (t < 64) { sb1[t] = b1[t]; sb2[t] = b2[t]; }
    __syncthreads();
    int lane = t & 63;
    int wid  = __builtin_amdgcn_readfirstlane(t >> 6);
    int base = blockIdx.x * 64 + wid * 16;
    int b    = blockIdx.x >> 4;        // 16 blocks per graph
    const float* Ab = A + (size_t)b*M_*H_;
    float* hsw = hS[wid];
    float* ht  = hidT[wid];
    for (int iter = 0; iter < 16; ++iter) {
        int i = base + iter;           // global node id
        hsw[lane] = h[(size_t)i*64 + lane];
        __syncthreads();               // (uniform across all waves)
        // C_f = b1[f] + sum_g h_i[g] * (W1a-W1b)[g][f]
        float c = sb1[lane];
        #pragma unroll
        for (int g = 0; g < 64; ++g) c += hsw[g] * swd[g*64 + lane];
        const int* kn = knn + (size_t)i*16;
        #pragma unroll
        for (int e = 0; e < 16; ++e) {
            int j = kn[e];
            float v = c + Ab[(size_t)j*64 + lane];
            ht[lane*RS + e] = fmaxf(v, 0.f);
        }
        __syncthreads();
        // GEMM: lane o accumulates msg[e][o] over f, then max over e
        float acc[16];
        #pragma unroll
        for (int e = 0; e < 16; ++e) acc[e] = 0.f;
        #pragma unroll 8
        for (int f = 0; f < 64; ++f) {
            float w = sw2[f*64 + lane];
            const float* hr = ht + f*RS;
            #pragma unroll
            for (int e = 0; e < 16; ++e) acc[e] += w * hr[e];
        }
        float m = acc[0];
        #pragma unroll
        for (int e = 1; e < 16; ++e) m = fmaxf(m, acc[e]);
        __syncthreads();               // protect hidT/hS WAR before next iter
        hout[(size_t)i*64 + lane] = m + sb2[lane];
    }
}

// ---------------- mean-pool + output MLP ----------------
__global__ __launch_bounds__(256) void pool_kernel(
    const float* __restrict__ h,    // [N,64]
    const float* __restrict__ w1,   // [64,32]
    const float* __restrict__ b1,   // [32]
    const float* __restrict__ w2,   // [32,1]
    const float* __restrict__ b2,   // [1]
    float* __restrict__ out)        // [B]
{
    __shared__ float part[4][64];
    __shared__ float g[64];
    __shared__ float hid[32];
    int t = threadIdx.x;
    int o = t & 63, p = t >> 6;
    int b = blockIdx.x;
    const float* hb = h + (size_t)b*M_*H_;
    float s = 0.f;
    for (int m = p; m < M_; m += 4) s += hb[(size_t)m*64 + o];
    part[p][o] = s;
    __syncthreads();
    if (t < 64) g[t] = (part[0][t] + part[1][t] + part[2][t] + part[3][t]) * (1.f/M_);
    __syncthreads();
    if (t < 32) {
        float a = b1[t];
        for (int f = 0; f < 64; ++f) a += g[f] * w1[f*32 + t];
        hid[t] = fmaxf(a, 0.f);
    }
    __syncthreads();
    if (t == 0) {
        float a = b2[0];
        for (int f = 0; f < 32; ++f) a += hid[f] * w2[f];
        out[b] = a;
    }
}

extern "C" void kernel_launch(void* const* d_in, const int* in_sizes, int n_in,
                              void* d_out, int out_size, void* d_ws, size_t ws_size,
                              hipStream_t stream)
{
    (void)in_sizes; (void)n_in; (void)out_size; (void)ws_size;
    const float* x      = (const float*)d_in[0];
    // d_in[1] = batch (int64) — equal-size graphs, unused
    const float* enc_w1 = (const float*)d_in[2];
    const float* enc_b1 = (const float*)d_in[3];
    const float* enc_w2 = (const float*)d_in[4];
    const float* enc_b2 = (const float*)d_in[5];
    const float* ec1_w1 = (const float*)d_in[6];
    const float* ec1_b1 = (const float*)d_in[7];
    const float* ec1_w2 = (const float*)d_in[8];
    const float* ec1_b2 = (const float*)d_in[9];
    const float* ec2_w1 = (const float*)d_in[10];
    const float* ec2_b1 = (const float*)d_in[11];
    const float* ec2_w2 = (const float*)d_in[12];
    const float* ec2_b2 = (const float*)d_in[13];
    const float* out_w1 = (const float*)d_in[14];
    const float* out_b1 = (const float*)d_in[15];
    const float* out_w2 = (const float*)d_in[16];
    const float* out_b2 = (const float*)d_in[17];

    char* ws = (char*)d_ws;
    float* h   = (float*)(ws);                               // 16 MB
    float* A   = (float*)(ws + (size_t)N_*64*4);             // 16 MB
    int*   idx = (int*)  (ws + (size_t)N_*64*4*2);           // 4 MB

    enc_kernel<<<N_/256, 256, 0, stream>>>(x, enc_w1, enc_b1, enc_w2, enc_b2, h);
    // layer 1
    knn_kernel <<<B_*16, 64, 0, stream>>>(h, idx);
    gemmA_kernel<<<N_/256, 256, 0, stream>>>(h, ec1_w1, A);
    edge_kernel<<<N_/64, 256, 0, stream>>>(h, A, idx, ec1_w1, ec1_b1, ec1_w2, ec1_b2, h);
    // layer 2
    knn_kernel <<<B_*16, 64, 0, stream>>>(h, idx);
    gemmA_kernel<<<N_/256, 256, 0, stream>>>(h, ec2_w1, A);
    edge_kernel<<<N_/64, 256, 0, stream>>>(h, A, idx, ec2_w1, ec2_b1, ec2_w2, ec2_b2, h);
    // pool + output MLP
    pool_kernel<<<B_, 256, 0, stream>>>(h, out_w1, out_b1, out_w2, out_b2, (float*)d_out);
}

// Round 3
// 1471.325 us; speedup vs baseline: 1.2186x; 1.2186x over previous
//
#include <hip/hip_runtime.h>
#include <math.h>

#define B_ 64
#define M_ 1024
#define K_ 16
#define H_ 64
#define N_ (B_*M_)   // 65536

#define GLD16(g, l) __builtin_amdgcn_global_load_lds( \
    (const __attribute__((address_space(1))) void*)(g), \
    (__attribute__((address_space(3))) void*)(l), 16, 0, 0)

// ---------------- encoder: h = relu(relu(x@w1+b1)@w2+b2) ----------------
__global__ __launch_bounds__(256) void enc_kernel(
    const float* __restrict__ x,     // [N,4]
    const float* __restrict__ w1,    // [4,32]
    const float* __restrict__ b1,    // [32]
    const float* __restrict__ w2,    // [32,64]
    const float* __restrict__ b2,    // [64]
    float* __restrict__ h)           // [N,64]
{
    __shared__ float sw1[4*32];
    __shared__ float sb1[32];
    __shared__ float sw2[32*64];
    __shared__ float sb2[64];
    int t = threadIdx.x;
    for (int i = t; i < 128; i += 256) sw1[i] = w1[i];
    if (t < 32) sb1[t] = b1[t];
    for (int i = t; i < 2048; i += 256) sw2[i] = w2[i];
    if (t < 64) sb2[t] = b2[t];
    __syncthreads();
    int n = blockIdx.x * 256 + t;
    float4 xv = *(const float4*)(x + (size_t)n*4);
    float hid[32];
    #pragma unroll
    for (int o = 0; o < 32; ++o) {
        float a = sb1[o] + xv.x*sw1[0*32+o] + xv.y*sw1[1*32+o]
                        + xv.z*sw1[2*32+o] + xv.w*sw1[3*32+o];
        hid[o] = fmaxf(a, 0.f);
    }
    float* hout = h + (size_t)n*64;
    #pragma unroll 4
    for (int oc = 0; oc < 16; ++oc) {
        float4 acc = make_float4(sb2[oc*4+0], sb2[oc*4+1], sb2[oc*4+2], sb2[oc*4+3]);
        #pragma unroll
        for (int f = 0; f < 32; ++f) {
            float4 w = *(const float4*)(sw2 + f*64 + oc*4);
            float hv = hid[f];
            acc.x += hv*w.x; acc.y += hv*w.y; acc.z += hv*w.z; acc.w += hv*w.w;
        }
        acc.x = fmaxf(acc.x,0.f); acc.y = fmaxf(acc.y,0.f);
        acc.z = fmaxf(acc.z,0.f); acc.w = fmaxf(acc.w,0.f);
        *(float4*)(hout + oc*4) = acc;
    }
}

// ---------------- A = h @ W1b  + sq = rowwise |h|^2 ----------------
__global__ __launch_bounds__(256) void gemmA_kernel(
    const float* __restrict__ h,
    const float* __restrict__ w1,   // [128,64]
    float* __restrict__ A,
    float* __restrict__ sq)         // [N]
{
    __shared__ float sw[64*64];
    int t = threadIdx.x;
    for (int idx = t; idx < 4096; idx += 256) sw[idx] = w1[4096 + idx];
    __syncthreads();
    int n = blockIdx.x * 256 + t;
    float4 hv[16];
    const float* src = h + (size_t)n*64;
    float s = 0.f;
    #pragma unroll
    for (int c = 0; c < 16; ++c) {
        float4 v = *(const float4*)(src + c*4);
        hv[c] = v;
        s += v.x*v.x + v.y*v.y + v.z*v.z + v.w*v.w;   // same order as R1 knn
    }
    sq[n] = s;
    float* dst = A + (size_t)n*64;
    #pragma unroll 2
    for (int oc = 0; oc < 16; ++oc) {
        float4 acc = make_float4(0.f,0.f,0.f,0.f);
        #pragma unroll
        for (int f = 0; f < 64; ++f) {
            float xv = ((const float*)hv)[f];
            float4 w = *(const float4*)(sw + f*64 + oc*4);
            acc.x += xv*w.x; acc.y += xv*w.y; acc.z += xv*w.z; acc.w += xv*w.w;
        }
        *(float4*)(dst + oc*4) = acc;
    }
}

// ---------------- kNN v2: block = 64 queries, 4 waves split each j-tile ----------------
// wave w processes rows [w*16, w*16+16) of each staged 64-row tile -> per-lane
// top-16 over 256 candidates; lexicographic LDS merge of the 4 partial lists.
__global__ __launch_bounds__(256, 3) void knn_kernel(
    const float* __restrict__ h,    // [N,64]
    const float* __restrict__ sqg,  // [N]
    unsigned short* __restrict__ knn)  // [N,16] (local node ids within graph)
{
    __shared__ float hj[64*64];     // 16 KB, one j-tile (flat copy of 64 rows)
    __shared__ float md[64*65];     // merge dists, pad 65 -> conflict-free
    __shared__ int   mi[64*65];     // merge indices
    int t    = threadIdx.x;
    int lane = t & 63;
    int w    = t >> 6;
    int b    = blockIdx.x >> 4;     // graph
    int qt   = blockIdx.x & 15;     // query tile
    int i    = qt*64 + lane;        // local query id within graph
    const float* hb  = h   + (size_t)b*M_*H_;
    const float* sqb = sqg + (size_t)b*M_;

    float4 hi[16];
    const float* hrow = hb + (size_t)i*64;
    #pragma unroll
    for (int c = 0; c < 16; ++c) hi[c] = *(const float4*)(hrow + c*4);
    float sqi = sqb[i];

    float bd[16]; int bi[16];
    #pragma unroll
    for (int k = 0; k < 16; ++k) { bd[k] = INFINITY; bi[k] = 0; }
    float worst = INFINITY; int wslot = 0;

    for (int jt = 0; jt < 16; ++jt) {
        __syncthreads();            // all waves done reading previous tile
        {   // stage 16 KB tile via global->LDS DMA, 4 chunks of 1 KB per wave
            const char* gsrc = (const char*)(hb + (size_t)jt*64*64);
            char* lbase = (char*)hj;
            #pragma unroll
            for (int k = 0; k < 4; ++k) {
                int off = w*4096 + k*1024;
                GLD16(gsrc + off + lane*16, lbase + off);
            }
        }
        __syncthreads();            // drains vmcnt before barrier
        int jbase = jt*64 + w*16;
        #pragma unroll 4
        for (int r = 0; r < 16; ++r) {
            const float* row = hj + (size_t)(w*16 + r)*64;
            float4 a0 = make_float4(0.f,0.f,0.f,0.f);
            #pragma unroll
            for (int c = 0; c < 16; ++c) {
                float4 v = *(const float4*)(row + c*4);
                a0.x += hi[c].x*v.x; a0.y += hi[c].y*v.y;
                a0.z += hi[c].z*v.z; a0.w += hi[c].w*v.w;
            }
            float dot = (a0.x + a0.y) + (a0.z + a0.w);
            int jg = jbase + r;
            float d = sqi + sqb[jg] - 2.f*dot;
            if ((jg != i) && (d < worst)) {
                #pragma unroll
                for (int k = 0; k < 16; ++k) if (k == wslot) { bd[k] = d; bi[k] = jg; }
                worst = bd[0]; wslot = 0;
                #pragma unroll
                for (int k = 1; k < 16; ++k) if (bd[k] > worst) { worst = bd[k]; wslot = k; }
            }
        }
    }

    // ---- merge the 4 per-wave partial top-16 lists ----
    __syncthreads();
    #pragma unroll
    for (int k = 0; k < 16; ++k) {
        md[lane*65 + w*16 + k] = bd[k];
        mi[lane*65 + w*16 + k] = bi[k];
    }
    __syncthreads();
    if (lane < 16) {
        int q = w*16 + lane;        // block-local query slot this thread merges
        float nbd[16]; int nbi[16];
        #pragma unroll
        for (int k = 0; k < 16; ++k) { nbd[k] = INFINITY; nbi[k] = 0x7fffffff; }
        float wst = INFINITY; int wsl = 0; int wix = 0x7fffffff;
        for (int k = 0; k < 64; ++k) {
            float d = md[q*65 + k];
            int  id = mi[q*65 + k];
            if ((d < wst) || (d == wst && id < wix)) {
                #pragma unroll
                for (int s = 0; s < 16; ++s) if (s == wsl) { nbd[s] = d; nbi[s] = id; }
                wst = nbd[0]; wsl = 0; wix = nbi[0];
                #pragma unroll
                for (int s = 1; s < 16; ++s)
                    if ((nbd[s] > wst) || (nbd[s] == wst && nbi[s] > wix))
                        { wst = nbd[s]; wsl = s; wix = nbi[s]; }
            }
        }
        // FIX: include the query-tile offset (R2 bug: wrote all tiles to rows 0..63)
        size_t gq = (size_t)b*M_ + (size_t)qt*64 + q;
        #pragma unroll
        for (int k = 0; k < 16; ++k) knn[gq*16 + k] = (unsigned short)nbi[k];
    }
}

// ---------------- EdgeConv: out_i = max_e ReLU(C_i + A_j)@W2 + b2 ----------------
#define RS 20   // padded row stride for hidT
__global__ __launch_bounds__(256) void edge_kernel(
    const float* __restrict__ h,     // [N,64] in (in-place out OK: only own row read)
    const float* __restrict__ A,     // [N,64]
    const unsigned short* __restrict__ knn, // [N,16] local idx
    const float* __restrict__ w1,    // [128,64]
    const float* __restrict__ b1,    // [64]
    const float* __restrict__ w2,    // [64,64]
    const float* __restrict__ b2,    // [64]
    float* __restrict__ hout)
{
    __shared__ float swd[64*64];   // W1a - W1b
    __shared__ float sw2[64*64];
    __shared__ float sb1[64], sb2[64];
    __shared__ float hS[4][64];
    __shared__ float hidT[4][64*RS];
    int t = threadIdx.x;
    for (int idx = t; idx < 4096; idx += 256) {
        swd[idx] = w1[idx] - w1[4096 + idx];
        sw2[idx] = w2[idx];
    }
    if (t < 64) { sb1[t] = b1[t]; sb2[t] = b2[t]; }
    __syncthreads();
    int lane = t & 63;
    int wid  = __builtin_amdgcn_readfirstlane(t >> 6);
    int base = blockIdx.x * 64 + wid * 16;
    int b    = blockIdx.x >> 4;        // 16 blocks per graph
    const float* Ab = A + (size_t)b*M_*H_;
    float* hsw = hS[wid];
    float* ht  = hidT[wid];
    for (int iter = 0; iter < 16; ++iter) {
        int i = base + iter;           // global node id
        hsw[lane] = h[(size_t)i*64 + lane];
        __syncthreads();               // (uniform across all waves)
        // C_f = b1[f] + sum_g h_i[g] * (W1a-W1b)[g][f]
        float c = sb1[lane];
        #pragma unroll
        for (int g = 0; g < 64; ++g) c += hsw[g] * swd[g*64 + lane];
        const unsigned short* kn = knn + (size_t)i*16;
        #pragma unroll
        for (int e = 0; e < 16; ++e) {
            int j = kn[e];
            float v = c + Ab[(size_t)j*64 + lane];
            ht[lane*RS + e] = fmaxf(v, 0.f);
        }
        __syncthreads();
        // GEMM: lane o accumulates msg[e][o] over f, then max over e
        float acc[16];
        #pragma unroll
        for (int e = 0; e < 16; ++e) acc[e] = 0.f;
        #pragma unroll 8
        for (int f = 0; f < 64; ++f) {
            float w = sw2[f*64 + lane];
            const float* hr = ht + f*RS;
            #pragma unroll
            for (int e = 0; e < 16; ++e) acc[e] += w * hr[e];
        }
        float m = acc[0];
        #pragma unroll
        for (int e = 1; e < 16; ++e) m = fmaxf(m, acc[e]);
        __syncthreads();               // protect hidT/hS WAR before next iter
        hout[(size_t)i*64 + lane] = m + sb2[lane];
    }
}

// ---------------- mean-pool + output MLP ----------------
__global__ __launch_bounds__(256) void pool_kernel(
    const float* __restrict__ h,    // [N,64]
    const float* __restrict__ w1,   // [64,32]
    const float* __restrict__ b1,   // [32]
    const float* __restrict__ w2,   // [32,1]
    const float* __restrict__ b2,   // [1]
    float* __restrict__ out)        // [B]
{
    __shared__ float part[4][64];
    __shared__ float g[64];
    __shared__ float hid[32];
    int t = threadIdx.x;
    int o = t & 63, p = t >> 6;
    int b = blockIdx.x;
    const float* hb = h + (size_t)b*M_*H_;
    float s = 0.f;
    for (int m = p; m < M_; m += 4) s += hb[(size_t)m*64 + o];
    part[p][o] = s;
    __syncthreads();
    if (t < 64) g[t] = (part[0][t] + part[1][t] + part[2][t] + part[3][t]) * (1.f/M_);
    __syncthreads();
    if (t < 32) {
        float a = b1[t];
        for (int f = 0; f < 64; ++f) a += g[f] * w1[f*32 + t];
        hid[t] = fmaxf(a, 0.f);
    }
    __syncthreads();
    if (t == 0) {
        float a = b2[0];
        for (int f = 0; f < 32; ++f) a += hid[f] * w2[f];
        out[b] = a;
    }
}

extern "C" void kernel_launch(void* const* d_in, const int* in_sizes, int n_in,
                              void* d_out, int out_size, void* d_ws, size_t ws_size,
                              hipStream_t stream)
{
    (void)in_sizes; (void)n_in; (void)out_size; (void)ws_size;
    const float* x      = (const float*)d_in[0];
    // d_in[1] = batch (int64) — equal-size graphs, unused
    const float* enc_w1 = (const float*)d_in[2];
    const float* enc_b1 = (const float*)d_in[3];
    const float* enc_w2 = (const float*)d_in[4];
    const float* enc_b2 = (const float*)d_in[5];
    const float* ec1_w1 = (const float*)d_in[6];
    const float* ec1_b1 = (const float*)d_in[7];
    const float* ec1_w2 = (const float*)d_in[8];
    const float* ec1_b2 = (const float*)d_in[9];
    const float* ec2_w1 = (const float*)d_in[10];
    const float* ec2_b1 = (const float*)d_in[11];
    const float* ec2_w2 = (const float*)d_in[12];
    const float* ec2_b2 = (const float*)d_in[13];
    const float* out_w1 = (const float*)d_in[14];
    const float* out_b1 = (const float*)d_in[15];
    const float* out_w2 = (const float*)d_in[16];
    const float* out_b2 = (const float*)d_in[17];

    // ws layout (34.25 MB total, proven envelope is >= 36 MB from R1):
    char* ws = (char*)d_ws;
    float*          h   = (float*)(ws);                                  // 16 MB
    float*          A   = (float*)(ws + (size_t)N_*64*4);                // 16 MB
    unsigned short* idx = (unsigned short*)(ws + (size_t)N_*64*4*2);     // 2 MB
    float*          sq  = (float*)(ws + (size_t)N_*64*4*2 + (size_t)N_*16*2); // 256 KB

    enc_kernel<<<N_/256, 256, 0, stream>>>(x, enc_w1, enc_b1, enc_w2, enc_b2, h);
    // layer 1 (gemmA also produces sq for knn)
    gemmA_kernel<<<N_/256, 256, 0, stream>>>(h, ec1_w1, A, sq);
    knn_kernel <<<B_*16, 256, 0, stream>>>(h, sq, idx);
    edge_kernel<<<N_/64, 256, 0, stream>>>(h, A, idx, ec1_w1, ec1_b1, ec1_w2, ec1_b2, h);
    // layer 2
    gemmA_kernel<<<N_/256, 256, 0, stream>>>(h, ec2_w1, A, sq);
    knn_kernel <<<B_*16, 256, 0, stream>>>(h, sq, idx);
    edge_kernel<<<N_/64, 256, 0, stream>>>(h, A, idx, ec2_w1, ec2_b1, ec2_w2, ec2_b2, h);
    // pool + output MLP
    pool_kernel<<<B_, 256, 0, stream>>>(h, out_w1, out_b1, out_w2, out_b2, (float*)d_out);
}

// Round 4
// 1175.671 us; speedup vs baseline: 1.5250x; 1.2515x over previous
//
#include <hip/hip_runtime.h>
#include <math.h>

#define B_ 64
#define M_ 1024
#define H_ 64
#define N_ (B_*M_)   // 65536

typedef _Float16 half8 __attribute__((ext_vector_type(8)));
typedef float  floatx4 __attribute__((ext_vector_type(4)));

#define MFMA16(a,b,c) __builtin_amdgcn_mfma_f32_16x16x32_f16(a,b,c,0,0,0)
#define MED3(a,b,c)   __builtin_amdgcn_fmed3f(a,b,c)

// ---------------- encoder: h = relu(relu(x@w1+b1)@w2+b2) (+ f16 split + sq) ------
__global__ __launch_bounds__(256) void enc_kernel(
    const float* __restrict__ x,     // [N,4]
    const float* __restrict__ w1,    // [4,32]
    const float* __restrict__ b1,    // [32]
    const float* __restrict__ w2,    // [32,64]
    const float* __restrict__ b2,    // [64]
    float* __restrict__ h,           // [N,64]
    _Float16* __restrict__ hhi,      // [N,64]
    _Float16* __restrict__ hlo,      // [N,64]
    float* __restrict__ sq)          // [N]
{
    __shared__ float sw1[4*32];
    __shared__ float sb1[32];
    __shared__ float sw2[32*64];
    __shared__ float sb2[64];
    int t = threadIdx.x;
    for (int i = t; i < 128; i += 256) sw1[i] = w1[i];
    if (t < 32) sb1[t] = b1[t];
    for (int i = t; i < 2048; i += 256) sw2[i] = w2[i];
    if (t < 64) sb2[t] = b2[t];
    __syncthreads();
    int n = blockIdx.x * 256 + t;
    float4 xv = *(const float4*)(x + (size_t)n*4);
    float hid[32];
    #pragma unroll
    for (int o = 0; o < 32; ++o) {
        float a = sb1[o] + xv.x*sw1[0*32+o] + xv.y*sw1[1*32+o]
                        + xv.z*sw1[2*32+o] + xv.w*sw1[3*32+o];
        hid[o] = fmaxf(a, 0.f);
    }
    float* hout = h + (size_t)n*64;
    float sqa = 0.f;
    #pragma unroll 4
    for (int oc = 0; oc < 16; ++oc) {
        float4 acc = make_float4(sb2[oc*4+0], sb2[oc*4+1], sb2[oc*4+2], sb2[oc*4+3]);
        #pragma unroll
        for (int f = 0; f < 32; ++f) {
            float4 w = *(const float4*)(sw2 + f*64 + oc*4);
            float hv = hid[f];
            acc.x += hv*w.x; acc.y += hv*w.y; acc.z += hv*w.z; acc.w += hv*w.w;
        }
        acc.x = fmaxf(acc.x,0.f); acc.y = fmaxf(acc.y,0.f);
        acc.z = fmaxf(acc.z,0.f); acc.w = fmaxf(acc.w,0.f);
        *(float4*)(hout + oc*4) = acc;
        sqa += acc.x*acc.x + acc.y*acc.y + acc.z*acc.z + acc.w*acc.w;
        union { _Float16 f[4]; uint2 u; } Hh, Hl;
        Hh.f[0]=(_Float16)acc.x; Hh.f[1]=(_Float16)acc.y;
        Hh.f[2]=(_Float16)acc.z; Hh.f[3]=(_Float16)acc.w;
        Hl.f[0]=(_Float16)(acc.x-(float)Hh.f[0]); Hl.f[1]=(_Float16)(acc.y-(float)Hh.f[1]);
        Hl.f[2]=(_Float16)(acc.z-(float)Hh.f[2]); Hl.f[3]=(_Float16)(acc.w-(float)Hh.f[3]);
        *(uint2*)(hhi + (size_t)n*64 + oc*4) = Hh.u;
        *(uint2*)(hlo + (size_t)n*64 + oc*4) = Hl.u;
    }
    sq[n] = sqa;
}

// ---------------- convert: h -> (hhi, hlo, sq)  (after edge layer 1) -------------
__global__ __launch_bounds__(256) void convert_kernel(
    const float* __restrict__ h,
    _Float16* __restrict__ hhi, _Float16* __restrict__ hlo,
    float* __restrict__ sq)
{
    int t = threadIdx.x, lane = t & 63, w = t >> 6;
    int base = blockIdx.x * 64 + w * 16;
    for (int it = 0; it < 16; ++it) {
        int i = base + it;
        float v = h[(size_t)i*64 + lane];
        _Float16 hi = (_Float16)v;
        _Float16 lo = (_Float16)(v - (float)hi);
        hhi[(size_t)i*64 + lane] = hi;
        hlo[(size_t)i*64 + lane] = lo;
        float s = v*v;
        #pragma unroll
        for (int off = 1; off < 64; off <<= 1) s += __shfl_xor(s, off, 64);
        if (lane == 0) sq[i] = s;
    }
}

// ---------------- A = h @ W1b  (W1b = rows 64..127 of w1) ----------------
__global__ __launch_bounds__(256) void gemmA_kernel(
    const float* __restrict__ h,
    const float* __restrict__ w1,   // [128,64]
    float* __restrict__ A)
{
    __shared__ float sw[64*64];
    int t = threadIdx.x;
    for (int idx = t; idx < 4096; idx += 256) sw[idx] = w1[4096 + idx];
    __syncthreads();
    int n = blockIdx.x * 256 + t;
    float4 hv[16];
    const float* src = h + (size_t)n*64;
    #pragma unroll
    for (int c = 0; c < 16; ++c) hv[c] = *(const float4*)(src + c*4);
    float* dst = A + (size_t)n*64;
    #pragma unroll 2
    for (int oc = 0; oc < 16; ++oc) {
        float4 acc = make_float4(0.f,0.f,0.f,0.f);
        #pragma unroll
        for (int f = 0; f < 64; ++f) {
            float xv = ((const float*)hv)[f];
            float4 w = *(const float4*)(sw + f*64 + oc*4);
            acc.x += xv*w.x; acc.y += xv*w.y; acc.z += xv*w.z; acc.w += xv*w.w;
        }
        *(float4*)(dst + oc*4) = acc;
    }
}

// ---------------- kNN v3: MFMA distances + med3 top-16 + tau two-pass ------------
// block = 64 queries (qt) x 1024 candidates; 4 waves split candidates (256 each).
// Rank score s = sq_j - 2*dot(h_i,h_j)  (sq_i constant per row; monotone in dist).
// dot via f16 split: hi*hi + hi*lo + lo*hi  (error ~3e-6 rel).
__global__ __launch_bounds__(256) void knn_kernel(
    const _Float16* __restrict__ hhi,
    const _Float16* __restrict__ hlo,
    const float* __restrict__ sqg,
    unsigned short* __restrict__ knn)    // [N,16]
{
    __shared__ float D[4][64*65];         // per-wave 64x64 score tile, pad 65
    __shared__ unsigned int cntL[64], cntE[64];
    __shared__ unsigned short eqbuf[64][16];
    int t = threadIdx.x, lane = t & 63, w = t >> 6;
    int g  = blockIdx.x >> 4;
    int qt = blockIdx.x & 15;
    const _Float16* hhig = hhi + (size_t)g*M_*64;
    const _Float16* hlog = hlo + (size_t)g*M_*64;
    const float*    sqb  = sqg + (size_t)g*M_;
    if (t < 64) { cntL[t] = 0; cntE[t] = 0; }

    // A fragments (queries), lane holds A[m=lane&15][k=(lane>>4)*8 + j]
    int m16  = lane & 15;
    int koct = (lane >> 4) * 8;
    half8 Ahi[4][2], Alo[4][2];
    #pragma unroll
    for (int rb = 0; rb < 4; ++rb) {
        const _Float16* ph = hhig + (size_t)(qt*64 + rb*16 + m16)*64;
        const _Float16* pl = hlog + (size_t)(qt*64 + rb*16 + m16)*64;
        Ahi[rb][0] = *(const half8*)(ph + koct);
        Ahi[rb][1] = *(const half8*)(ph + 32 + koct);
        Alo[rb][0] = *(const half8*)(pl + koct);
        Alo[rb][1] = *(const half8*)(pl + 32 + koct);
    }
    float* Dw   = D[w];
    int    crow = (lane >> 4) * 4;   // C/D: col=lane&15, row=(lane>>4)*4+reg
    float  bd[16];
    #pragma unroll
    for (int k = 0; k < 16; ++k) bd[k] = INFINITY;
    float tau = 0.f;
    size_t gq = (size_t)g*M_ + qt*64 + lane;

    for (int pass = 0; pass < 2; ++pass) {
        for (int cc = 0; cc < 4; ++cc) {
            int cbase = w*256 + cc*64;     // local candidate base
            half8 Bhi[4][2], Blo[4][2];
            #pragma unroll
            for (int cb = 0; cb < 4; ++cb) {
                const _Float16* ph = hhig + (size_t)(cbase + cb*16 + m16)*64;
                const _Float16* pl = hlog + (size_t)(cbase + cb*16 + m16)*64;
                Bhi[cb][0] = *(const half8*)(ph + koct);
                Bhi[cb][1] = *(const half8*)(ph + 32 + koct);
                Blo[cb][0] = *(const half8*)(pl + koct);
                Blo[cb][1] = *(const half8*)(pl + 32 + koct);
            }
            #pragma unroll
            for (int rb = 0; rb < 4; ++rb) {
                #pragma unroll
                for (int cb = 0; cb < 4; ++cb) {
                    floatx4 acc = {0.f, 0.f, 0.f, 0.f};
                    acc = MFMA16(Ahi[rb][0], Bhi[cb][0], acc);
                    acc = MFMA16(Ahi[rb][1], Bhi[cb][1], acc);
                    acc = MFMA16(Ahi[rb][0], Blo[cb][0], acc);
                    acc = MFMA16(Ahi[rb][1], Blo[cb][1], acc);
                    acc = MFMA16(Alo[rb][0], Bhi[cb][0], acc);
                    acc = MFMA16(Alo[rb][1], Bhi[cb][1], acc);
                    #pragma unroll
                    for (int r = 0; r < 4; ++r)
                        Dw[(rb*16 + crow + r)*65 + cb*16 + m16] = acc[r];
                }
            }
            // lane = query row; scan this wave's 64 candidates
            const float* drow = Dw + lane*65;
            bool isdiag = (cbase == qt*64);
            for (int c = 0; c < 64; ++c) {
                float dot = drow[c];
                float s = fmaf(-2.f, dot, sqb[cbase + c]);
                if (isdiag && c == lane) s = INFINITY;
                if (pass == 0) {
                    float nb0 = fminf(bd[0], s);
                    #pragma unroll
                    for (int k = 15; k >= 1; --k) bd[k] = MED3(s, bd[k-1], bd[k]);
                    bd[0] = nb0;
                } else {
                    if (s < tau) {
                        unsigned p = atomicAdd(&cntL[lane], 1u);
                        if (p < 16u) knn[gq*16 + p] = (unsigned short)(cbase + c);
                    } else if (s == tau) {
                        unsigned p = atomicAdd(&cntE[lane], 1u);
                        if (p < 16u) eqbuf[lane][p] = (unsigned short)(cbase + c);
                    }
                }
            }
        }
        if (pass == 0) {
            // merge 4 per-wave sorted value lists -> exact 16th-smallest tau per query
            __syncthreads();                 // all waves done with their D tiles
            float* md = D[0];                // alias D[0] as mdAll[64][65]
            #pragma unroll
            for (int k = 0; k < 16; ++k) md[lane*65 + w*16 + k] = bd[k];
            __syncthreads();
            float b2[16];
            #pragma unroll
            for (int k = 0; k < 16; ++k) b2[k] = INFINITY;
            const float* mrow = md + lane*65;
            for (int c = 0; c < 64; ++c) {
                float s = mrow[c];
                float nb0 = fminf(b2[0], s);
                #pragma unroll
                for (int k = 15; k >= 1; --k) b2[k] = MED3(s, b2[k-1], b2[k]);
                b2[0] = nb0;
            }
            tau = b2[15];
            __syncthreads();                 // release md before pass2 overwrites D[0]
        }
    }
    __syncthreads();
    if (t < 64) {
        unsigned cL = cntL[t]; if (cL > 16u) cL = 16u;
        for (unsigned k = cL; k < 16u; ++k)
            knn[((size_t)g*M_ + qt*64 + t)*16 + k] = eqbuf[t][k - cL];
    }
}

// ---------------- EdgeConv: out_i = max_e ReLU(C_i + A_j)@W2 + b2 ----------------
#define RS 20   // padded row stride for hidT
__global__ __launch_bounds__(256) void edge_kernel(
    const float* __restrict__ h,     // [N,64] in (in-place out OK: only own row read)
    const float* __restrict__ A,     // [N,64]
    const unsigned short* __restrict__ knn, // [N,16] local idx
    const float* __restrict__ w1,    // [128,64]
    const float* __restrict__ b1,    // [64]
    const float* __restrict__ w2,    // [64,64]
    const float* __restrict__ b2,    // [64]
    float* __restrict__ hout)
{
    __shared__ float swd[64*64];   // W1a - W1b
    __shared__ float sw2[64*64];
    __shared__ float sb1[64], sb2[64];
    __shared__ float hS[4][64];
    __shared__ float hidT[4][64*RS];
    int t = threadIdx.x;
    for (int idx = t; idx < 4096; idx += 256) {
        swd[idx] = w1[idx] - w1[4096 + idx];
        sw2[idx] = w2[idx];
    }
    if (t < 64) { sb1[t] = b1[t]; sb2[t] = b2[t]; }
    __syncthreads();
    int lane = t & 63;
    int wid  = __builtin_amdgcn_readfirstlane(t >> 6);
    int base = blockIdx.x * 64 + wid * 16;
    int b    = blockIdx.x >> 4;        // 16 blocks per graph
    const float* Ab = A + (size_t)b*M_*H_;
    float* hsw = hS[wid];
    float* ht  = hidT[wid];
    for (int iter = 0; iter < 16; ++iter) {
        int i = base + iter;           // global node id
        hsw[lane] = h[(size_t)i*64 + lane];
        __syncthreads();
        float c = sb1[lane];
        #pragma unroll
        for (int g = 0; g < 64; ++g) c += hsw[g] * swd[g*64 + lane];
        const unsigned short* kn = knn + (size_t)i*16;
        #pragma unroll
        for (int e = 0; e < 16; ++e) {
            int j = kn[e];
            float v = c + Ab[(size_t)j*64 + lane];
            ht[lane*RS + e] = fmaxf(v, 0.f);
        }
        __syncthreads();
        float acc[16];
        #pragma unroll
        for (int e = 0; e < 16; ++e) acc[e] = 0.f;
        #pragma unroll 8
        for (int f = 0; f < 64; ++f) {
            float w = sw2[f*64 + lane];
            const float* hr = ht + f*RS;
            #pragma unroll
            for (int e = 0; e < 16; ++e) acc[e] += w * hr[e];
        }
        float m = acc[0];
        #pragma unroll
        for (int e = 1; e < 16; ++e) m = fmaxf(m, acc[e]);
        __syncthreads();
        hout[(size_t)i*64 + lane] = m + sb2[lane];
    }
}

// ---------------- mean-pool + output MLP ----------------
__global__ __launch_bounds__(256) void pool_kernel(
    const float* __restrict__ h,    // [N,64]
    const float* __restrict__ w1,   // [64,32]
    const float* __restrict__ b1,   // [32]
    const float* __restrict__ w2,   // [32,1]
    const float* __restrict__ b2,   // [1]
    float* __restrict__ out)        // [B]
{
    __shared__ float part[4][64];
    __shared__ float g[64];
    __shared__ float hid[32];
    int t = threadIdx.x;
    int o = t & 63, p = t >> 6;
    int b = blockIdx.x;
    const float* hb = h + (size_t)b*M_*H_;
    float s = 0.f;
    for (int m = p; m < M_; m += 4) s += hb[(size_t)m*64 + o];
    part[p][o] = s;
    __syncthreads();
    if (t < 64) g[t] = (part[0][t] + part[1][t] + part[2][t] + part[3][t]) * (1.f/M_);
    __syncthreads();
    if (t < 32) {
        float a = b1[t];
        for (int f = 0; f < 64; ++f) a += g[f] * w1[f*32 + t];
        hid[t] = fmaxf(a, 0.f);
    }
    __syncthreads();
    if (t == 0) {
        float a = b2[0];
        for (int f = 0; f < 32; ++f) a += hid[f] * w2[f];
        out[b] = a;
    }
}

extern "C" void kernel_launch(void* const* d_in, const int* in_sizes, int n_in,
                              void* d_out, int out_size, void* d_ws, size_t ws_size,
                              hipStream_t stream)
{
    (void)in_sizes; (void)n_in; (void)out_size; (void)ws_size;
    const float* x      = (const float*)d_in[0];
    const float* enc_w1 = (const float*)d_in[2];
    const float* enc_b1 = (const float*)d_in[3];
    const float* enc_w2 = (const float*)d_in[4];
    const float* enc_b2 = (const float*)d_in[5];
    const float* ec1_w1 = (const float*)d_in[6];
    const float* ec1_b1 = (const float*)d_in[7];
    const float* ec1_w2 = (const float*)d_in[8];
    const float* ec1_b2 = (const float*)d_in[9];
    const float* ec2_w1 = (const float*)d_in[10];
    const float* ec2_b1 = (const float*)d_in[11];
    const float* ec2_w2 = (const float*)d_in[12];
    const float* ec2_b2 = (const float*)d_in[13];
    const float* out_w1 = (const float*)d_in[14];
    const float* out_b1 = (const float*)d_in[15];
    const float* out_w2 = (const float*)d_in[16];
    const float* out_b2 = (const float*)d_in[17];

    // ws layout, 34.25 MB total. Region2 (16 MB) time-shared:
    //   (hhi|hlo) live producer->knn;  A lives gemmA->edge.  Never overlap.
    char* ws = (char*)d_ws;
    float*          h   = (float*)(ws);                                  // 16 MB
    char*           r2  = ws + (size_t)N_*64*4;                          // 16 MB
    _Float16*       hhi = (_Float16*)r2;                                 //  8 MB
    _Float16*       hlo = (_Float16*)(r2 + (size_t)N_*64*2);             //  8 MB
    float*          A   = (float*)r2;                                    // 16 MB (alias)
    unsigned short* idx = (unsigned short*)(ws + (size_t)N_*64*4*2);     //  2 MB
    float*          sq  = (float*)(ws + (size_t)N_*64*4*2 + (size_t)N_*16*2); // 256 KB

    enc_kernel<<<N_/256, 256, 0, stream>>>(x, enc_w1, enc_b1, enc_w2, enc_b2,
                                           h, hhi, hlo, sq);
    // layer 1
    knn_kernel <<<B_*16, 256, 0, stream>>>(hhi, hlo, sq, idx);
    gemmA_kernel<<<N_/256, 256, 0, stream>>>(h, ec1_w1, A);   // clobbers hhi/hlo (dead)
    edge_kernel<<<N_/64, 256, 0, stream>>>(h, A, idx, ec1_w1, ec1_b1, ec1_w2, ec1_b2, h);
    // layer 2
    convert_kernel<<<N_/64, 256, 0, stream>>>(h, hhi, hlo, sq); // clobbers A (dead)
    knn_kernel <<<B_*16, 256, 0, stream>>>(hhi, hlo, sq, idx);
    gemmA_kernel<<<N_/256, 256, 0, stream>>>(h, ec2_w1, A);
    edge_kernel<<<N_/64, 256, 0, stream>>>(h, A, idx, ec2_w1, ec2_b1, ec2_w2, ec2_b2, h);
    // pool + output MLP
    pool_kernel<<<B_, 256, 0, stream>>>(h, out_w1, out_b1, out_w2, out_b2, (float*)d_out);
}